// Round 20
// baseline (211.381 us; speedup 1.0000x reference)
//
#include <hip/hip_runtime.h>
#include <math.h>

#define T_SEQ 2048
#define NH 16
#define HD 64
#define EMB 1024
#define NBATCH 4
#define M_ROWS 8192  // NBATCH*T_SEQ

typedef __attribute__((ext_vector_type(8))) short short8;
typedef __attribute__((ext_vector_type(4))) float f32x4;

__device__ __forceinline__ unsigned short f2bf(float f) {
  unsigned int u = __float_as_uint(f);
  u += 0x7FFF + ((u >> 16) & 1);
  return (unsigned short)(u >> 16);
}

__device__ __forceinline__ float fast_exp2(float x) {
  float r;
  asm("v_exp_f32 %0, %1" : "=v"(r) : "v"(x));
  return r;
}

__device__ __forceinline__ void load_lds16(const void* g, void* l) {
  __builtin_amdgcn_global_load_lds((const __attribute__((address_space(1))) void*)g,
                                   (__attribute__((address_space(3))) void*)l, 16, 0, 0);
}

// ---------------- converts ----------------
__global__ void k_cvt(const float* __restrict__ in, unsigned short* __restrict__ out, int n4) {
  int i = blockIdx.x * blockDim.x + threadIdx.x;
  if (i < n4) {
    float4 v = reinterpret_cast<const float4*>(in)[i];
    ushort4 o;
    o.x = f2bf(v.x); o.y = f2bf(v.y); o.z = f2bf(v.z); o.w = f2bf(v.w);
    reinterpret_cast<ushort4*>(out)[i] = o;
  }
}

// transpose + cvt: w[K][N] f32 -> wt[N][K] bf16, via 64x64 LDS tile (coalesced both sides)
__global__ __launch_bounds__(256) void k_cvtT(const float* __restrict__ w,
                                              unsigned short* __restrict__ wt,
                                              int K, int N) {
  __shared__ unsigned short tile[64][66];
  const int tid = threadIdx.x;
  const int k0 = blockIdx.y * 64, n0 = blockIdx.x * 64;
  const int tc = (tid & 15) * 4;
  const int tr = tid >> 4;
#pragma unroll
  for (int p = 0; p < 4; ++p) {
    const int kr = p * 16 + tr;
    float4 v = *reinterpret_cast<const float4*>(&w[(size_t)(k0 + kr) * N + n0 + tc]);
    tile[kr][tc + 0] = f2bf(v.x); tile[kr][tc + 1] = f2bf(v.y);
    tile[kr][tc + 2] = f2bf(v.z); tile[kr][tc + 3] = f2bf(v.w);
  }
  __syncthreads();
#pragma unroll
  for (int p = 0; p < 4; ++p) {
    const int nr = p * 16 + tr;
    ushort4 o;
    o.x = tile[tc + 0][nr]; o.y = tile[tc + 1][nr];
    o.z = tile[tc + 2][nr]; o.w = tile[tc + 3][nr];
    *reinterpret_cast<ushort4*>(&wt[(size_t)(n0 + nr) * K + k0 + tc]) = o;
  }
}

// ---------------- GEMM: small-BK ring, 3 slots -> 3 blocks/CU (TLP lever) ----------------
// R9 data path (proven) with ring 4->3 slots: 48KB LDS -> 3 blocks/CU = 6 waves/SIMD (+50%
// TLP vs R9's 2 blocks).  BM=128, BN=128, BK=32.  512 thr = 8 waves (2m x 4n), per-wave
// 64x32 out.  Stage-ahead-2: at tile t, in flight = stage(t+1); stage(t+2) issued after
// top-of-t barrier.  Waits: vmcnt(2) steady (outstanding before wait = stage(t)[issued t-2],
// stage(t+1)[issued t-1]; retire through stage(t)), vmcnt(0) at t=nkb-1.  Slot hazards:
// stage(t+2) overwrites slot (t+2)%3 = (t-1)%3 whose readers all retired before the top-of-t
// barrier (compiler lgkm waits precede their MFMAs, MFMAs precede barrier in program order);
// in-flight DMAs always target distinct slots (t+1)%3 != (t+2)%3.
// Grid balance: QKV 1536 blocks = 2 exact rounds of 768 resident; proj 512 = 1 round.
// MODE 0: write float to Cout. MODE 1: scatter bf16 q,k -> [B,H,T,64]; v -> V^T [B,H,64,T].
template <int MODE>
__global__ __launch_bounds__(512, 6) void k_gemmp(
    const unsigned short* __restrict__ A,
    const unsigned short* __restrict__ Bt,
    const float* __restrict__ bias,
    float* __restrict__ Cout,
    unsigned short* __restrict__ qh, unsigned short* __restrict__ kh,
    unsigned short* __restrict__ vh,
    int N, int K)
{
  extern __shared__ __align__(16) unsigned short lds[];  // 3 slots x 8192 shorts (A 4096 + B 4096)

  const int tid = threadIdx.x;
  const int w = tid >> 6, lane = tid & 63;
  const int lo = lane & 15, hi = lane >> 4;
  const int wm = w >> 2, wn = w & 3;

  // XCD-aware swizzle (nwg % 8 == 0 for both launches)
  const int nwg = gridDim.x * gridDim.y;
  int flat = blockIdx.y * gridDim.x + blockIdx.x;
  flat = (flat & 7) * (nwg >> 3) + (flat >> 3);
  const int tm = flat / gridDim.x, tn = flat % gridDim.x;

  // staging: thread -> (row = tid>>2, chunk = tid&3); source chunk pre-permuted
  const int srow = tid >> 2, sc = tid & 3;
  const int scol = (sc ^ ((srow >> 1) & 3)) * 8;
  const unsigned short* Abase = A  + (size_t)(tm * 128 + srow) * K + scol;
  const unsigned short* Bbase = Bt + (size_t)(tn * 128 + srow) * K + scol;
  const int wbase = w * 512;  // dest: wave-uniform base + lane*16B == tid*8 shorts

  const int nkb = K >> 5;  // BK=32
  const int rk = (lo >> 1) & 3;  // read-side XOR key

  f32x4 acc[4][2] = {};

  auto stage = [&](int slot, int kb) {  // exactly 2 global_load_lds (the vmcnt unit)
    unsigned short* s = lds + slot * 8192;
    load_lds16(Abase + kb * 32, s + wbase);
    load_lds16(Bbase + kb * 32, s + 4096 + wbase);
  };

  // prologue: 2 tiles in flight
  stage(0, 0);
  if (nkb > 1) stage(1, 1);

  for (int t = 0; t < nkb; ++t) {
    if (t + 1 < nkb) asm volatile("s_waitcnt vmcnt(2)" ::: "memory");  // tile t landed; t+1 in flight
    else             asm volatile("s_waitcnt vmcnt(0)" ::: "memory");
    __builtin_amdgcn_s_barrier();   // tile t visible to all; tile t-1 reads retired by all

    if (t + 2 < nkb) stage((t + 2) % 3, t + 2);

    const unsigned short* sA = lds + (t % 3) * 8192;
    const unsigned short* sB = sA + 4096;

    short8 a[4], b[2];
#pragma unroll
    for (int m = 0; m < 4; ++m)
      a[m] = *reinterpret_cast<const short8*>(&sA[(wm * 64 + m * 16 + lo) * 32 + ((hi ^ rk) * 8)]);
#pragma unroll
    for (int n = 0; n < 2; ++n)
      b[n] = *reinterpret_cast<const short8*>(&sB[(wn * 32 + n * 16 + lo) * 32 + ((hi ^ rk) * 8)]);

    __builtin_amdgcn_s_setprio(1);
#pragma unroll
    for (int m = 0; m < 4; ++m)
#pragma unroll
      for (int n = 0; n < 2; ++n)
        acc[m][n] = __builtin_amdgcn_mfma_f32_16x16x32_bf16(a[m], b[n], acc[m][n], 0, 0, 0);
    __builtin_amdgcn_s_setprio(0);
  }

#pragma unroll
  for (int m = 0; m < 4; ++m) {
#pragma unroll
    for (int n = 0; n < 2; ++n) {
      const int col = tn * 128 + wn * 32 + n * 16 + lo;
      const float bs = bias[col];
#pragma unroll
      for (int r = 0; r < 4; ++r) {
        const int row = tm * 128 + wm * 64 + m * 16 + hi * 4 + r;
        const float v = acc[m][n][r] + bs;
        if (MODE == 0) {
          Cout[(size_t)row * N + col] = v;
        } else {
          const int sec = col >> 10, jj = col & 1023;
          const int hh = jj >> 6, d = jj & 63;
          const int b2 = row >> 11, tt = row & 2047;
          if (sec == 2) {
            vh[(size_t)((b2 * NH + hh) * HD + d) * T_SEQ + tt] = f2bf(v);  // V^T [B,H,d,T]
          } else {
            unsigned short* dst = sec == 0 ? qh : kh;
            dst[(size_t)((b2 * NH + hh) * T_SEQ + tt) * HD + d] = f2bf(v);
          }
        }
      }
    }
  }
}

// ---------------- flash attention (R16, verified) ----------------
#define C1 0.1803368801111f
#define M2 12.0f

__device__ __forceinline__ void stage2(const unsigned short* src, const int off[2],
                                       unsigned short* dstbase, int w) {
#pragma unroll
  for (int j = 0; j < 2; ++j)
    load_lds16(src + off[j], dstbase + (2 * w + j) * 512);
}

template <bool FIRST, bool LAST>
__device__ __forceinline__ void attn_tile(
    int kvb, int nkvb,  // BOTH in kv-row units
    int qw, int w, int lo, int hi,
    const short8& aq0, const short8& aq1,
    const unsigned short* __restrict__ Kp,
    const unsigned short* __restrict__ VT,
    const int koff[2], const int voff[2],
    unsigned short* kc, unsigned short* kn, unsigned short* vc,
    unsigned short* pw,
    f32x4 o[4], float lsum[4])
{
  {
    const int vb2[2] = {kvb + voff[0], kvb + voff[1]};
    stage2(VT, vb2, vc, w);
  }
  if (!LAST) {
    const int kb2[2] = {nkvb * HD + koff[0], nkvb * HD + koff[1]};
    stage2(Kp, kb2, kn, w);
  }

  if (FIRST)
    asm volatile("s_waitcnt vmcnt(0)\n\ts_barrier" ::: "memory");

  const int swz = lo & 7;
  f32x4 s[4];
#pragma unroll
  for (int n = 0; n < 4; ++n) {
    const int row = (n * 16 + lo) * 64;
    short8 bk0 = *reinterpret_cast<const short8*>(&kc[row + ((hi) ^ swz) * 8]);
    short8 bk1 = *reinterpret_cast<const short8*>(&kc[row + ((4 + hi) ^ swz) * 8]);
    f32x4 z = {};
    z = __builtin_amdgcn_mfma_f32_16x16x32_bf16(aq0, bk0, z, 0, 0, 0);
    s[n] = __builtin_amdgcn_mfma_f32_16x16x32_bf16(aq1, bk1, z, 0, 0, 0);
  }

  const int lb3 = lo >> 3, l7 = lo & 7;
#pragma unroll
  for (int r = 0; r < 4; ++r) {
    const int qrow = qw + hi * 4 + r;
    const int q = hi * 4 + r, qk7 = q & 7;
#pragma unroll
    for (int n = 0; n < 4; ++n) {
      float e = fast_exp2(fmaf(s[n][r], C1, -M2));
      if (LAST) {
        const int kv = kvb + n * 16 + lo;
        if (kv > qrow) e = 0.f;
      }
      lsum[r] += e;
      pw[q * 64 + (((n * 2 + lb3) ^ qk7) * 8) + l7] = f2bf(e);
    }
  }

  asm volatile("s_waitcnt vmcnt(0)\n\ts_barrier" ::: "memory");

#pragma unroll
  for (int kk = 0; kk < 2; ++kk) {
    short8 ap = *reinterpret_cast<const short8*>(&pw[lo * 64 + ((kk * 4 + hi) ^ swz) * 8]);
#pragma unroll
    for (int n = 0; n < 4; ++n) {
      const int row = (n * 16 + lo) * 64;
      short8 bv = *reinterpret_cast<const short8*>(&vc[row + ((kk * 4 + hi) ^ swz) * 8]);
      o[n] = __builtin_amdgcn_mfma_f32_16x16x32_bf16(ap, bv, o[n], 0, 0, 0);
    }
  }
}

__device__ __forceinline__ void attn_phase(
    int qb, int w, int lo, int hi,
    const unsigned short* __restrict__ Q,
    const unsigned short* __restrict__ Kp,
    const unsigned short* __restrict__ VT,
    const int koff[2], const int voff[2],
    unsigned short* kbuf0, unsigned short* kbuf1,
    unsigned short* vbuf0, unsigned short* vbuf1,
    unsigned short* pw,
    unsigned short* __restrict__ y, int b, int h)
{
  __builtin_amdgcn_s_barrier();

  const int qw = qb * 64 + w * 16;

  short8 aq0 = *reinterpret_cast<const short8*>(Q + (size_t)(qw + lo) * HD + hi * 8);
  short8 aq1 = *reinterpret_cast<const short8*>(Q + (size_t)(qw + lo) * HD + 32 + hi * 8);

  f32x4 o[4] = {};
  float lsum[4] = {0.f, 0.f, 0.f, 0.f};

  {
    const int kb2[2] = {koff[0], koff[1]};
    stage2(Kp, kb2, kbuf0, w);
  }

  const int nt = qb + 1;
  if (nt == 1) {
    attn_tile<true, true>(0, 0, qw, w, lo, hi, aq0, aq1, Kp, VT, koff, voff,
                          kbuf0, kbuf1, vbuf0, pw, o, lsum);
  } else {
    attn_tile<true, false>(0, 64, qw, w, lo, hi, aq0, aq1, Kp, VT, koff, voff,
                           kbuf0, kbuf1, vbuf0, pw, o, lsum);
    for (int t = 1; t < nt - 1; ++t) {
      unsigned short* kc = (t & 1) ? kbuf1 : kbuf0;
      unsigned short* kn = (t & 1) ? kbuf0 : kbuf1;
      unsigned short* vc = (t & 1) ? vbuf1 : vbuf0;
      attn_tile<false, false>(t * 64, (t + 1) * 64, qw, w, lo, hi, aq0, aq1, Kp, VT,
                              koff, voff, kc, kn, vc, pw, o, lsum);
    }
    const int t = nt - 1;
    unsigned short* kc = (t & 1) ? kbuf1 : kbuf0;
    unsigned short* kn = (t & 1) ? kbuf0 : kbuf1;
    unsigned short* vc = (t & 1) ? vbuf1 : vbuf0;
    attn_tile<false, true>(t * 64, 0, qw, w, lo, hi, aq0, aq1, Kp, VT, koff, voff,
                           kc, kn, vc, pw, o, lsum);
  }

#pragma unroll
  for (int r = 0; r < 4; ++r) {
    float v = lsum[r];
    v += __shfl_xor(v, 1);
    v += __shfl_xor(v, 2);
    v += __shfl_xor(v, 4);
    v += __shfl_xor(v, 8);
    lsum[r] = 1.0f / v;
  }

#pragma unroll
  for (int n = 0; n < 4; ++n)
#pragma unroll
    for (int r = 0; r < 4; ++r) {
      const int qrow = qw + hi * 4 + r;
      const float val = o[n][r] * lsum[r];
      y[(size_t)(b * T_SEQ + qrow) * EMB + h * HD + n * 16 + lo] = f2bf(val);
    }
}

__global__ __launch_bounds__(256, 4) void k_attn(
    const unsigned short* __restrict__ qh,
    const unsigned short* __restrict__ kh,
    const unsigned short* __restrict__ vt,
    unsigned short* __restrict__ y)
{
  __shared__ __align__(16) unsigned short kbuf[2][64 * 64];
  __shared__ __align__(16) unsigned short vbuf[2][64 * 64];
  __shared__ __align__(16) unsigned short pbuf[4 * 16 * 64];

  const int tid = threadIdx.x;
  const int w = tid >> 6, lane = tid & 63;
  const int lo = lane & 15, hi = lane >> 4;
  const int bh = blockIdx.y;
  const int b = bh >> 4, h = bh & 15;

  const unsigned short* Q  = qh + (size_t)bh * T_SEQ * HD;
  const unsigned short* Kp = kh + (size_t)bh * T_SEQ * HD;
  const unsigned short* VT = vt + (size_t)bh * T_SEQ * HD;
  unsigned short* pw = pbuf + w * 1024;

  const int l3 = lane >> 3, l7 = lane & 7;
  const int sw8 = (l7 ^ l3) * 8;
  int koff[2], voff[2];
#pragma unroll
  for (int j = 0; j < 2; ++j) {
    const int row = (2 * w + j) * 8 + l3;
    koff[j] = row * HD + sw8;
    voff[j] = row * T_SEQ + sw8;
  }

  attn_phase(blockIdx.x, w, lo, hi, Q, Kp, VT, koff, voff,
             kbuf[0], kbuf[1], vbuf[0], vbuf[1], pw, y, b, h);
  attn_phase(31 - blockIdx.x, w, lo, hi, Q, Kp, VT, koff, voff,
             kbuf[0], kbuf[1], vbuf[0], vbuf[1], pw, y, b, h);
}

// ---------------- launch ----------------
extern "C" void kernel_launch(void* const* d_in, const int* in_sizes, int n_in,
                              void* d_out, int out_size, void* d_ws, size_t ws_size,
                              hipStream_t stream) {
  const float* x      = (const float*)d_in[0];
  const float* w_qkv  = (const float*)d_in[1];
  const float* b_qkv  = (const float*)d_in[2];
  const float* w_proj = (const float*)d_in[3];
  const float* b_proj = (const float*)d_in[4];
  float* out = (float*)d_out;

  char* ws = (char*)d_ws;
  unsigned short* xb     = (unsigned short*)(ws);                 // 16.78 MB (reused as y)
  unsigned short* wqkvT  = (unsigned short*)(ws + 16777216);      // 6.29 MB
  unsigned short* wprojT = (unsigned short*)(ws + 23068672);      // 2.10 MB
  unsigned short* qhb    = (unsigned short*)(ws + 25165824);      // 16.78 MB
  unsigned short* khb    = (unsigned short*)(ws + 41943040);      // 16.78 MB
  unsigned short* vtb    = (unsigned short*)(ws + 58720256);      // 16.78 MB (V^T)
  unsigned short* yb     = xb;  // x no longer needed after QKV GEMM

  const int dynLds = 3 * 8192 * 2;  // 49152 B (3-slot ring) -> 3 blocks/CU
  (void)hipFuncSetAttribute(reinterpret_cast<const void*>(k_gemmp<1>),
                            hipFuncAttributeMaxDynamicSharedMemorySize, dynLds);
  (void)hipFuncSetAttribute(reinterpret_cast<const void*>(k_gemmp<0>),
                            hipFuncAttributeMaxDynamicSharedMemorySize, dynLds);

  k_cvt<<<8192, 256, 0, stream>>>(x, xb, (M_ROWS * EMB) / 4);
  k_cvtT<<<dim3(48, 16), 256, 0, stream>>>(w_qkv, wqkvT, EMB, 3 * EMB);
  k_cvtT<<<dim3(16, 16), 256, 0, stream>>>(w_proj, wprojT, EMB, EMB);

  k_gemmp<1><<<dim3(24, 64), 512, dynLds, stream>>>(xb, wqkvT, b_qkv, nullptr,
                                                    qhb, khb, vtb, 3 * EMB, EMB);
  k_attn<<<dim3(T_SEQ / 128, NBATCH * NH), 256, 0, stream>>>(qhb, khb, vtb, yb);
  k_gemmp<0><<<dim3(8, 64), 512, dynLds, stream>>>(yb, wprojT, b_proj, out,
                                                   nullptr, nullptr, nullptr, EMB, EMB);
}

// Round 21
// 206.859 us; speedup vs baseline: 1.0219x; 1.0219x over previous
//
#include <hip/hip_runtime.h>
#include <math.h>

#define T_SEQ 2048
#define NH 16
#define HD 64
#define EMB 1024
#define NBATCH 4
#define M_ROWS 8192  // NBATCH*T_SEQ

typedef __attribute__((ext_vector_type(8))) short short8;
typedef __attribute__((ext_vector_type(4))) float f32x4;

__device__ __forceinline__ unsigned short f2bf(float f) {
  unsigned int u = __float_as_uint(f);
  u += 0x7FFF + ((u >> 16) & 1);
  return (unsigned short)(u >> 16);
}

__device__ __forceinline__ float fast_exp2(float x) {
  float r;
  asm("v_exp_f32 %0, %1" : "=v"(r) : "v"(x));
  return r;
}

__device__ __forceinline__ void load_lds16(const void* g, void* l) {
  __builtin_amdgcn_global_load_lds((const __attribute__((address_space(1))) void*)g,
                                   (__attribute__((address_space(3))) void*)l, 16, 0, 0);
}

// ---------------- converts ----------------
__global__ void k_cvt(const float* __restrict__ in, unsigned short* __restrict__ out, int n4) {
  int i = blockIdx.x * blockDim.x + threadIdx.x;
  if (i < n4) {
    float4 v = reinterpret_cast<const float4*>(in)[i];
    ushort4 o;
    o.x = f2bf(v.x); o.y = f2bf(v.y); o.z = f2bf(v.z); o.w = f2bf(v.w);
    reinterpret_cast<ushort4*>(out)[i] = o;
  }
}

// transpose + cvt: w[K][N] f32 -> wt[N][K] bf16, via 64x64 LDS tile (coalesced both sides)
__global__ __launch_bounds__(256) void k_cvtT(const float* __restrict__ w,
                                              unsigned short* __restrict__ wt,
                                              int K, int N) {
  __shared__ unsigned short tile[64][66];
  const int tid = threadIdx.x;
  const int k0 = blockIdx.y * 64, n0 = blockIdx.x * 64;
  const int tc = (tid & 15) * 4;
  const int tr = tid >> 4;
#pragma unroll
  for (int p = 0; p < 4; ++p) {
    const int kr = p * 16 + tr;
    float4 v = *reinterpret_cast<const float4*>(&w[(size_t)(k0 + kr) * N + n0 + tc]);
    tile[kr][tc + 0] = f2bf(v.x); tile[kr][tc + 1] = f2bf(v.y);
    tile[kr][tc + 2] = f2bf(v.z); tile[kr][tc + 3] = f2bf(v.w);
  }
  __syncthreads();
#pragma unroll
  for (int p = 0; p < 4; ++p) {
    const int nr = p * 16 + tr;
    ushort4 o;
    o.x = tile[tc + 0][nr]; o.y = tile[tc + 1][nr];
    o.z = tile[tc + 2][nr]; o.w = tile[tc + 3][nr];
    *reinterpret_cast<ushort4*>(&wt[(size_t)(n0 + nr) * K + k0 + tc]) = o;
  }
}

// ---------------- GEMM: m97-replica — 128x128 tile, BK=64, 4 waves of 64x64 ----------------
// The one proven-on-HW geometry not yet tried: 256 thr = 2x2 waves, per-wave 64x64
// (acc[4][4] = 64 VGPR), BK=64, single-buffered 32KB LDS, simple 2-barrier K-loop
// {bar; stage w16; bar; compute}.  Per wave per K-step: 16 ds_read_b128 feed 32 MFMA
// (0.5 KB/MFMA — vs 0.75 in all my 64x32 variants).  4 blocks/CU (= 16 waves/CU)
// provides the cross-block overlap that hides the stage drain (m114 mechanism; m97
// measured 874 TF at 4096^3 with this exact shape).  XOR swizzle (verified, 0 conflicts):
// source chunk = c ^ (row&7), read chunk = (kk*4+hi) ^ (lo&7).  XCD-aware block swizzle.
// MODE 0: write float to Cout. MODE 1: scatter bf16 q,k -> [B,H,T,64]; v -> V^T [B,H,64,T].
template <int MODE>
__global__ __launch_bounds__(256, 4) void k_gemmq(
    const unsigned short* __restrict__ A,
    const unsigned short* __restrict__ Bt,
    const float* __restrict__ bias,
    float* __restrict__ Cout,
    unsigned short* __restrict__ qh, unsigned short* __restrict__ kh,
    unsigned short* __restrict__ vh,
    int N, int K)
{
  __shared__ __align__(16) unsigned short sA[128 * 64];  // 16 KB
  __shared__ __align__(16) unsigned short sB[128 * 64];  // 16 KB

  const int tid = threadIdx.x;
  const int w = tid >> 6, lane = tid & 63;
  const int lo = lane & 15, hi = lane >> 4;
  const int wm = w >> 1, wn = w & 1;

  // XCD-aware swizzle (nwg % 8 == 0 for both launches)
  const int nwg = gridDim.x * gridDim.y;
  int flat = blockIdx.y * gridDim.x + blockIdx.x;
  flat = (flat & 7) * (nwg >> 3) + (flat >> 3);
  const int tm = flat / gridDim.x, tn = flat % gridDim.x;

  // staging: thread -> row r0 = tid>>3 (0..31), chunk = tid&7 (row has 8 x 16B chunks)
  const int r0 = tid >> 3;
  const int scol = ((tid & 7) ^ (r0 & 7)) * 8;   // pre-swizzled source chunk; key (row&7) invariant under +32
  const unsigned short* Ab = A  + (size_t)(tm * 128 + r0) * K + scol;
  const unsigned short* Bb = Bt + (size_t)(tn * 128 + r0) * K + scol;
  const int dsto = tid * 8;                      // = r0*64 + (tid&7)*8  (linear dest)

  const int nkb = K >> 6;  // BK=64
  const int swz = lo & 7;

  f32x4 acc[4][4] = {};

  for (int kb = 0; kb < nkb; ++kb) {
    __syncthreads();  // prior tile's reads retired everywhere
    const int k0 = kb << 6;
#pragma unroll
    for (int i = 0; i < 4; ++i) {   // 4 row-groups of 32; 8 loads/thread total
      load_lds16(Ab + (size_t)(i * 32) * K + k0, sA + i * 2048 + dsto);
      load_lds16(Bb + (size_t)(i * 32) * K + k0, sB + i * 2048 + dsto);
    }
    __syncthreads();  // drains vmcnt -> tile visible

#pragma unroll
    for (int kk = 0; kk < 2; ++kk) {
      short8 a[4], b[4];
#pragma unroll
      for (int m = 0; m < 4; ++m)
        a[m] = *reinterpret_cast<const short8*>(
            &sA[(wm * 64 + m * 16 + lo) * 64 + ((kk * 4 + hi) ^ swz) * 8]);
#pragma unroll
      for (int n = 0; n < 4; ++n)
        b[n] = *reinterpret_cast<const short8*>(
            &sB[(wn * 64 + n * 16 + lo) * 64 + ((kk * 4 + hi) ^ swz) * 8]);
      __builtin_amdgcn_s_setprio(1);
#pragma unroll
      for (int m = 0; m < 4; ++m)
#pragma unroll
        for (int n = 0; n < 4; ++n)
          acc[m][n] = __builtin_amdgcn_mfma_f32_16x16x32_bf16(a[m], b[n], acc[m][n], 0, 0, 0);
      __builtin_amdgcn_s_setprio(0);
    }
  }

#pragma unroll
  for (int m = 0; m < 4; ++m) {
#pragma unroll
    for (int n = 0; n < 4; ++n) {
      const int col = tn * 128 + wn * 64 + n * 16 + lo;
      const float bs = bias[col];
#pragma unroll
      for (int r = 0; r < 4; ++r) {
        const int row = tm * 128 + wm * 64 + m * 16 + hi * 4 + r;
        const float v = acc[m][n][r] + bs;
        if (MODE == 0) {
          Cout[(size_t)row * N + col] = v;
        } else {
          const int sec = col >> 10, jj = col & 1023;
          const int hh = jj >> 6, d = jj & 63;
          const int b2 = row >> 11, tt = row & 2047;
          if (sec == 2) {
            vh[(size_t)((b2 * NH + hh) * HD + d) * T_SEQ + tt] = f2bf(v);  // V^T [B,H,d,T]
          } else {
            unsigned short* dst = sec == 0 ? qh : kh;
            dst[(size_t)((b2 * NH + hh) * T_SEQ + tt) * HD + d] = f2bf(v);
          }
        }
      }
    }
  }
}

// ---------------- flash attention (R16, verified) ----------------
#define C1 0.1803368801111f
#define M2 12.0f

__device__ __forceinline__ void stage2(const unsigned short* src, const int off[2],
                                       unsigned short* dstbase, int w) {
#pragma unroll
  for (int j = 0; j < 2; ++j)
    load_lds16(src + off[j], dstbase + (2 * w + j) * 512);
}

template <bool FIRST, bool LAST>
__device__ __forceinline__ void attn_tile(
    int kvb, int nkvb,  // BOTH in kv-row units
    int qw, int w, int lo, int hi,
    const short8& aq0, const short8& aq1,
    const unsigned short* __restrict__ Kp,
    const unsigned short* __restrict__ VT,
    const int koff[2], const int voff[2],
    unsigned short* kc, unsigned short* kn, unsigned short* vc,
    unsigned short* pw,
    f32x4 o[4], float lsum[4])
{
  {
    const int vb2[2] = {kvb + voff[0], kvb + voff[1]};
    stage2(VT, vb2, vc, w);
  }
  if (!LAST) {
    const int kb2[2] = {nkvb * HD + koff[0], nkvb * HD + koff[1]};
    stage2(Kp, kb2, kn, w);
  }

  if (FIRST)
    asm volatile("s_waitcnt vmcnt(0)\n\ts_barrier" ::: "memory");

  const int swz = lo & 7;
  f32x4 s[4];
#pragma unroll
  for (int n = 0; n < 4; ++n) {
    const int row = (n * 16 + lo) * 64;
    short8 bk0 = *reinterpret_cast<const short8*>(&kc[row + ((hi) ^ swz) * 8]);
    short8 bk1 = *reinterpret_cast<const short8*>(&kc[row + ((4 + hi) ^ swz) * 8]);
    f32x4 z = {};
    z = __builtin_amdgcn_mfma_f32_16x16x32_bf16(aq0, bk0, z, 0, 0, 0);
    s[n] = __builtin_amdgcn_mfma_f32_16x16x32_bf16(aq1, bk1, z, 0, 0, 0);
  }

  const int lb3 = lo >> 3, l7 = lo & 7;
#pragma unroll
  for (int r = 0; r < 4; ++r) {
    const int qrow = qw + hi * 4 + r;
    const int q = hi * 4 + r, qk7 = q & 7;
#pragma unroll
    for (int n = 0; n < 4; ++n) {
      float e = fast_exp2(fmaf(s[n][r], C1, -M2));
      if (LAST) {
        const int kv = kvb + n * 16 + lo;
        if (kv > qrow) e = 0.f;
      }
      lsum[r] += e;
      pw[q * 64 + (((n * 2 + lb3) ^ qk7) * 8) + l7] = f2bf(e);
    }
  }

  asm volatile("s_waitcnt vmcnt(0)\n\ts_barrier" ::: "memory");

#pragma unroll
  for (int kk = 0; kk < 2; ++kk) {
    short8 ap = *reinterpret_cast<const short8*>(&pw[lo * 64 + ((kk * 4 + hi) ^ swz) * 8]);
#pragma unroll
    for (int n = 0; n < 4; ++n) {
      const int row = (n * 16 + lo) * 64;
      short8 bv = *reinterpret_cast<const short8*>(&vc[row + ((kk * 4 + hi) ^ swz) * 8]);
      o[n] = __builtin_amdgcn_mfma_f32_16x16x32_bf16(ap, bv, o[n], 0, 0, 0);
    }
  }
}

__device__ __forceinline__ void attn_phase(
    int qb, int w, int lo, int hi,
    const unsigned short* __restrict__ Q,
    const unsigned short* __restrict__ Kp,
    const unsigned short* __restrict__ VT,
    const int koff[2], const int voff[2],
    unsigned short* kbuf0, unsigned short* kbuf1,
    unsigned short* vbuf0, unsigned short* vbuf1,
    unsigned short* pw,
    unsigned short* __restrict__ y, int b, int h)
{
  __builtin_amdgcn_s_barrier();

  const int qw = qb * 64 + w * 16;

  short8 aq0 = *reinterpret_cast<const short8*>(Q + (size_t)(qw + lo) * HD + hi * 8);
  short8 aq1 = *reinterpret_cast<const short8*>(Q + (size_t)(qw + lo) * HD + 32 + hi * 8);

  f32x4 o[4] = {};
  float lsum[4] = {0.f, 0.f, 0.f, 0.f};

  {
    const int kb2[2] = {koff[0], koff[1]};
    stage2(Kp, kb2, kbuf0, w);
  }

  const int nt = qb + 1;
  if (nt == 1) {
    attn_tile<true, true>(0, 0, qw, w, lo, hi, aq0, aq1, Kp, VT, koff, voff,
                          kbuf0, kbuf1, vbuf0, pw, o, lsum);
  } else {
    attn_tile<true, false>(0, 64, qw, w, lo, hi, aq0, aq1, Kp, VT, koff, voff,
                           kbuf0, kbuf1, vbuf0, pw, o, lsum);
    for (int t = 1; t < nt - 1; ++t) {
      unsigned short* kc = (t & 1) ? kbuf1 : kbuf0;
      unsigned short* kn = (t & 1) ? kbuf0 : kbuf1;
      unsigned short* vc = (t & 1) ? vbuf1 : vbuf0;
      attn_tile<false, false>(t * 64, (t + 1) * 64, qw, w, lo, hi, aq0, aq1, Kp, VT,
                              koff, voff, kc, kn, vc, pw, o, lsum);
    }
    const int t = nt - 1;
    unsigned short* kc = (t & 1) ? kbuf1 : kbuf0;
    unsigned short* kn = (t & 1) ? kbuf0 : kbuf1;
    unsigned short* vc = (t & 1) ? vbuf1 : vbuf0;
    attn_tile<false, true>(t * 64, 0, qw, w, lo, hi, aq0, aq1, Kp, VT, koff, voff,
                           kc, kn, vc, pw, o, lsum);
  }

#pragma unroll
  for (int r = 0; r < 4; ++r) {
    float v = lsum[r];
    v += __shfl_xor(v, 1);
    v += __shfl_xor(v, 2);
    v += __shfl_xor(v, 4);
    v += __shfl_xor(v, 8);
    lsum[r] = 1.0f / v;
  }

#pragma unroll
  for (int n = 0; n < 4; ++n)
#pragma unroll
    for (int r = 0; r < 4; ++r) {
      const int qrow = qw + hi * 4 + r;
      const float val = o[n][r] * lsum[r];
      y[(size_t)(b * T_SEQ + qrow) * EMB + h * HD + n * 16 + lo] = f2bf(val);
    }
}

__global__ __launch_bounds__(256, 4) void k_attn(
    const unsigned short* __restrict__ qh,
    const unsigned short* __restrict__ kh,
    const unsigned short* __restrict__ vt,
    unsigned short* __restrict__ y)
{
  __shared__ __align__(16) unsigned short kbuf[2][64 * 64];
  __shared__ __align__(16) unsigned short vbuf[2][64 * 64];
  __shared__ __align__(16) unsigned short pbuf[4 * 16 * 64];

  const int tid = threadIdx.x;
  const int w = tid >> 6, lane = tid & 63;
  const int lo = lane & 15, hi = lane >> 4;
  const int bh = blockIdx.y;
  const int b = bh >> 4, h = bh & 15;

  const unsigned short* Q  = qh + (size_t)bh * T_SEQ * HD;
  const unsigned short* Kp = kh + (size_t)bh * T_SEQ * HD;
  const unsigned short* VT = vt + (size_t)bh * T_SEQ * HD;
  unsigned short* pw = pbuf + w * 1024;

  const int l3 = lane >> 3, l7 = lane & 7;
  const int sw8 = (l7 ^ l3) * 8;
  int koff[2], voff[2];
#pragma unroll
  for (int j = 0; j < 2; ++j) {
    const int row = (2 * w + j) * 8 + l3;
    koff[j] = row * HD + sw8;
    voff[j] = row * T_SEQ + sw8;
  }

  attn_phase(blockIdx.x, w, lo, hi, Q, Kp, VT, koff, voff,
             kbuf[0], kbuf[1], vbuf[0], vbuf[1], pw, y, b, h);
  attn_phase(31 - blockIdx.x, w, lo, hi, Q, Kp, VT, koff, voff,
             kbuf[0], kbuf[1], vbuf[0], vbuf[1], pw, y, b, h);
}

// ---------------- launch ----------------
extern "C" void kernel_launch(void* const* d_in, const int* in_sizes, int n_in,
                              void* d_out, int out_size, void* d_ws, size_t ws_size,
                              hipStream_t stream) {
  const float* x      = (const float*)d_in[0];
  const float* w_qkv  = (const float*)d_in[1];
  const float* b_qkv  = (const float*)d_in[2];
  const float* w_proj = (const float*)d_in[3];
  const float* b_proj = (const float*)d_in[4];
  float* out = (float*)d_out;

  char* ws = (char*)d_ws;
  unsigned short* xb     = (unsigned short*)(ws);                 // 16.78 MB (reused as y)
  unsigned short* wqkvT  = (unsigned short*)(ws + 16777216);      // 6.29 MB
  unsigned short* wprojT = (unsigned short*)(ws + 23068672);      // 2.10 MB
  unsigned short* qhb    = (unsigned short*)(ws + 25165824);      // 16.78 MB
  unsigned short* khb    = (unsigned short*)(ws + 41943040);      // 16.78 MB
  unsigned short* vtb    = (unsigned short*)(ws + 58720256);      // 16.78 MB (V^T)
  unsigned short* yb     = xb;  // x no longer needed after QKV GEMM

  k_cvt<<<8192, 256, 0, stream>>>(x, xb, (M_ROWS * EMB) / 4);
  k_cvtT<<<dim3(48, 16), 256, 0, stream>>>(w_qkv, wqkvT, EMB, 3 * EMB);
  k_cvtT<<<dim3(16, 16), 256, 0, stream>>>(w_proj, wprojT, EMB, EMB);

  k_gemmq<1><<<dim3(24, 64), 256, 0, stream>>>(xb, wqkvT, b_qkv, nullptr,
                                               qhb, khb, vtb, 3 * EMB, EMB);
  k_attn<<<dim3(T_SEQ / 128, NBATCH * NH), 256, 0, stream>>>(qhb, khb, vtb, yb);
  k_gemmq<0><<<dim3(8, 64), 256, 0, stream>>>(yb, wprojT, b_proj, out,
                                              nullptr, nullptr, nullptr, EMB, EMB);
}